// Round 19
// baseline (58.074 us; speedup 1.0000x reference)
//
#include <hip/hip_runtime.h>
#include <hip/hip_bf16.h>
#include <cmath>

// Problem dims (fixed by reference setup_inputs)
#define BB 2
#define HH 480
#define WW 640
#define DD 256
#define HC 60
#define WC 80
#define NN (HC*WC)            // 4800

#define DET_BLOCKS 300
#define SUMSQ_NB ((NN + 255)/256)         // 19
#define GEOM_NB ((BB*NN + 255)/256)       // 38
#define P1_BLOCKS (16*SUMSQ_NB + GEOM_NB) // 304 + 38 = 342

// fp32 fallback tiling
#define NTILES64 (NN/64)                  // 75
#define DESC_BLOCKS_F32 (BB*NTILES64*NTILES64)  // 11250
// mfma tiling: 192x192 block, 8 waves (2x4) of 96x48 (6x3 frags), BK=32, 2-buf
#define TS4 192
#define BK 32
#define NT192 (NN/TS4)                    // 25
#define BLK192 (NT192*NT192)              // 625
#define GEMM_BLOCKS (BB*BLK192)           // 1250
#define CORR_BLOCKS (BB*NN/8)             // 1200 (8 waves/block, 1 n per wave)
#define DET_ROLE_BLOCKS (2*DET_BLOCKS)    // 600
#define DESC_PARTIALS (GEMM_BLOCKS + CORR_BLOCKS)       // 2450
#define DESC_GRID (DESC_PARTIALS + DET_ROLE_BLOCKS)     // 3050

// ws layout (float offsets)
#define OFF_DET0  0                       // 300*4
#define OFF_DET1  2048                    // 300*4
#define OFF_INVA  16384                   // BB*NN (fallback path only)
#define OFF_INVB  (OFF_INVA + BB*NN)
#define OFF_WRW   (OFF_INVB + BB*NN)
#define OFF_WCL   (OFF_WRW + BB*NN)
#define OFF_VMC   (OFF_WCL + BB*NN)
#define OFF_WVMC  (OFF_VMC + BB*NN)
#define OFF_SQP   (OFF_WVMC + BB*NN)      // 73984; 16*NN = 76800 floats
#define OFF_DESCP (OFF_SQP + 16*NN)       // 150784; 2450 partials
#define OFF_TA    172032                  // bf16 desc, k-major [B][32][N][8] (normalized*masked)
#define TA_FLOATS (BB*NN*DD/2)            // 1228800 floats (bf16 storage)
#define OFF_TB    (OFF_TA + TA_FLOATS)
#define WS_NEED   ((size_t)(OFF_TB + TA_FLOATS) * 4)

typedef __attribute__((ext_vector_type(8))) short short8;
typedef __attribute__((ext_vector_type(4))) float f32x4;

__device__ inline float bf2f(unsigned short u)
{
    unsigned int x = ((unsigned int)u) << 16;
    return __builtin_bit_cast(float, x);
}

// ---------------- detector-loss accum (fast native log) ----------------
__device__ inline void det_accum(float p, float h, float v,
                                 float& posl, float& negl, float& npos, float& vsum)
{
    float omp = 1.f - p;
    if (h == 1.0f) {
        posl += __logf(p + 1e-7f) * omp*omp * v;
        npos += 1.f;
    }
    if (h < 1.0f) {
        float oh = 1.f - h;
        float w4 = oh*oh; w4 *= w4;
        negl += __logf(omp + 1e-7f) * p*p * w4 * v;
    }
    vsum += v;
}

// parametric over block size (nthr = 256 or 512)
__device__ inline void det_role(
    int set, int db, int tid, int nthr,
    const float* __restrict__ pred0, const float* __restrict__ hmap0, const float* __restrict__ vm0,
    const float* __restrict__ pred1, const float* __restrict__ hmap1, const float* __restrict__ vm1,
    float* __restrict__ ws, float* __restrict__ red)
{
    const float4* pred = (const float4*)(set ? pred1 : pred0);
    const float4* hmap = (const float4*)(set ? hmap1 : hmap0);
    const float4* vm   = (const float4*)(set ? vm1   : vm0);
    float* partials = ws + (set ? OFF_DET1 : OFF_DET0);

    float posl = 0.f, negl = 0.f, npos = 0.f, vsum = 0.f;
    const int total4 = BB*HH*WW/4;        // 307200
    for (int i = db*nthr + tid; i < total4; i += DET_BLOCKS*nthr) {
        float4 p = pred[i], h = hmap[i], v = vm[i];
        det_accum(p.x, h.x, v.x, posl, negl, npos, vsum);
        det_accum(p.y, h.y, v.y, posl, negl, npos, vsum);
        det_accum(p.z, h.z, v.z, posl, negl, npos, vsum);
        det_accum(p.w, h.w, v.w, posl, negl, npos, vsum);
    }
    float vals[4] = {posl, negl, npos, vsum};
    for (int j = 0; j < 4; ++j) {
        red[tid] = vals[j]; __syncthreads();
        for (int s = nthr >> 1; s > 0; s >>= 1) { if (tid < s) red[tid] += red[tid+s]; __syncthreads(); }
        if (tid == 0) partials[db*4 + j] = red[0];
        __syncthreads();
    }
}

// ---------------- shared helpers ----------------
__device__ inline float bilin_cell(const float* __restrict__ x, int i, int j)
{
    float sr = (i + 0.5f) * ((float)HH/(float)HC) - 0.5f;
    sr = fminf(fmaxf(sr, 0.f), (float)(HH-1));
    int r0 = (int)floorf(sr); int r1 = min(r0+1, HH-1); float wr = sr - (float)r0;
    float sc = (j + 0.5f) * ((float)WW/(float)WC) - 0.5f;
    sc = fminf(fmaxf(sc, 0.f), (float)(WW-1));
    int c0 = (int)floorf(sc); int c1 = min(c0+1, WW-1); float wc = sc - (float)c0;
    float v00 = x[r0*WW+c0], v01 = x[r0*WW+c1];
    float v10 = x[r1*WW+c0], v11 = x[r1*WW+c1];
    float e0 = v00*(1.f-wr) + v10*wr;
    float e1 = v01*(1.f-wr) + v11*wr;
    return e0*(1.f-wc) + e1*wc;
}

__device__ inline void prep_geom(int idx, const float* __restrict__ vm,
                                 const float* __restrict__ wvm,
                                 const float* __restrict__ Hmat, float* __restrict__ ws)
{
    int b = idx / NN, n = idx % NN;
    int i = n / WC, j = n % WC;
    float px = (float)(j*8 + 4), py = (float)(i*8 + 4);   // (col, row)
    const float* Hb = Hmat + b*9;  // Hmat shape (B,1,3,3)
    float w0 = Hb[0]*px + Hb[1]*py + Hb[2];
    float w1 = Hb[3]*px + Hb[4]*py + Hb[5];
    float w2 = Hb[6]*px + Hb[7]*py + Hb[8];
    ws[OFF_WRW + idx] = w1 / w2;   // warped row
    ws[OFF_WCL + idx] = w0 / w2;   // warped col
    ws[OFF_VMC  + idx] = (bilin_cell(vm  + (size_t)b*HH*WW, i, j) > 0.5f) ? 1.f : 0.f;
    ws[OFF_WVMC + idx] = (bilin_cell(wvm + (size_t)b*HH*WW, i, j) > 0.5f) ? 1.f : 0.f;
}

// ---- phase1: sumsq partials (coalesced) + geometry/masks ----
__global__ __launch_bounds__(256) void phase1_kernel(
    const float* __restrict__ desc, const float* __restrict__ wdesc,
    const float* __restrict__ vm, const float* __restrict__ wvm,
    const float* __restrict__ Hmat, float* __restrict__ ws)
{
    const int bidx = blockIdx.x;
    if (bidx < 16*SUMSQ_NB) {
        const int combo = bidx / SUMSQ_NB;         // 0..15
        const int nb    = bidx % SUMSQ_NB;
        const int z  = combo >> 2;                 // b*2 + which
        const int dc = combo & 3;                  // 64-d chunk
        const int n  = nb*256 + threadIdx.x;
        if (n >= NN) return;
        const float* src = ((z & 1) ? wdesc : desc) + (size_t)(z >> 1)*DD*NN;
        float s = 0.f;
        const int d0 = dc*64;
        #pragma unroll 8
        for (int d = d0; d < d0 + 64; ++d) {
            float v = src[(size_t)d*NN + n];
            s = fmaf(v, v, s);
        }
        ws[OFF_SQP + ((size_t)z*4 + dc)*NN + n] = s;
        return;
    }
    const int idx = (bidx - 16*SUMSQ_NB)*256 + threadIdx.x;
    if (idx >= BB*NN) return;
    prep_geom(idx, vm, wvm, Hmat, ws);
}

// ---- prep (fallback): norms via direct column loop + geometry ----
__global__ __launch_bounds__(256) void prep_kernel_full(
    const float* __restrict__ desc, const float* __restrict__ wdesc,
    const float* __restrict__ vm, const float* __restrict__ wvm,
    const float* __restrict__ Hmat, float* __restrict__ ws)
{
    int idx = blockIdx.x*256 + threadIdx.x;
    if (idx >= BB*NN) return;
    int b = idx / NN, n = idx % NN;

    const float* a  = desc  + (size_t)b*DD*NN + n;
    const float* bp = wdesc + (size_t)b*DD*NN + n;
    float sa = 0.f, sb = 0.f;
    for (int d = 0; d < DD; ++d) {
        float x = a[(size_t)d*NN];  sa = fmaf(x, x, sa);
        float y = bp[(size_t)d*NN]; sb = fmaf(y, y, sb);
    }
    ws[OFF_INVA + idx] = 1.f / fmaxf(sqrtf(sa), 1e-12f);
    ws[OFF_INVB + idx] = 1.f / fmaxf(sqrtf(sb), 1e-12f);
    prep_geom(idx, vm, wvm, Hmat, ws);
}

// ---- standalone det (fallback path) ----
__global__ __launch_bounds__(256) void det_kernel(
    const float* __restrict__ pred0, const float* __restrict__ hmap0, const float* __restrict__ vm0,
    const float* __restrict__ pred1, const float* __restrict__ hmap1, const float* __restrict__ vm1,
    float* __restrict__ ws)
{
    __shared__ float red[256];
    det_role(blockIdx.x / DET_BLOCKS, blockIdx.x % DET_BLOCKS, threadIdx.x, 256,
             pred0, hmap0, vm0, pred1, hmap1, vm1, ws, red);
}

// -------- transpose + NORMALIZE(inline from SQP) + MASK + bf16 pack --------
__global__ __launch_bounds__(256) void transpose_kernel(
    const float* __restrict__ desc, const float* __restrict__ wdesc,
    unsigned short* __restrict__ ta, unsigned short* __restrict__ tb,
    const float* __restrict__ ws)
{
    const int nb = blockIdx.x * 64;
    const int db = blockIdx.y * 64;
    const int z  = blockIdx.z;           // b*2 + which
    const int b  = z >> 1;
    const float* src = (z & 1) ? wdesc : desc;
    unsigned short* dst = (z & 1) ? tb : ta;
    src += (size_t)b*DD*NN;
    dst += (size_t)b*NN*DD;

    __shared__ float tile[64][65];
    const int tr = threadIdx.x >> 6;     // 0..3 (wave id)
    const int tc = threadIdx.x & 63;
    #pragma unroll
    for (int i = 0; i < 16; ++i) {
        int d = db + i*4 + tr;
        tile[i*4 + tr][tc] = src[(size_t)d*NN + nb + tc];
    }
    __syncthreads();
    const int n = nb + tc;
    const int gidx = b*NN + n;
    float ss = 0.f;
    #pragma unroll
    for (int k = 0; k < 4; ++k)
        ss += ws[OFF_SQP + ((size_t)z*4 + k)*NN + n];
    const float inv  = 1.f / fmaxf(sqrtf(ss), 1e-12f);
    const float mask = (z & 1) ? ws[OFF_WVMC + gidx] : ws[OFF_VMC + gidx];
    const float scl  = inv * mask;
    #pragma unroll
    for (int gg = 0; gg < 2; ++gg) {
        int g = tr + gg*4;               // 0..7 within this 64-d tile
        short8 v8;
        #pragma unroll
        for (int j = 0; j < 8; ++j) {
            float v = tile[g*8 + j][tc] * scl;
            __hip_bfloat16 h = __float2bfloat16(v);
            v8[j] = (short)__builtin_bit_cast(unsigned short, h);
        }
        int sg = (db >> 3) + g;          // global slot 0..31
        *(short8*)(dst + ((size_t)sg*NN + nb + tc)*8) = v8;   // coalesced 16B/lane
    }
}

// ---------------- MFMA descriptor loss v18: 192x192, 8 waves, 2-buf --------
// Grid = DET -> CORR -> GEMM roles, 512 threads/block.
// GEMM role: 192x192 block, 8 waves (2x4) of 96x48 (6x3 frags 16x16x32),
// BK=32, DOUBLE-buffered LDS (48 KB -> 3 blocks/CU, 24 waves/CU), ONE
// s_barrier per K-step. STAGE(t+1) issued AFTER barrier(t) — safe because
// all waves past barrier(t) consumed buf[(t-1)&1] (= buf[(t+1)&1]) via
// MFMA(t-1)'s operand drain. At the wait point only stage t is outstanding,
// so vmcnt(0) is exactly the counted wait (no over-drain).
// Lean epilogue sum += relu(acc-0.2). CORR/DET roles unchanged.
__global__ __launch_bounds__(512, 4) void desc_mfma(
    const unsigned short* __restrict__ ta, const unsigned short* __restrict__ tb,
    const float* __restrict__ pred0, const float* __restrict__ hmap0, const float* __restrict__ vm0,
    const float* __restrict__ pred1, const float* __restrict__ hmap1, const float* __restrict__ vm1,
    const float* __restrict__ ws, float* __restrict__ partials)
{
    __shared__ unsigned short As[2][TS4*BK];   // 24 KB
    __shared__ unsigned short Bs[2][TS4*BK];   // 48 KB total
    __shared__ float corr_red[8];

    const int bidx = blockIdx.x;
    const int tid  = threadIdx.x;
    const int lane = tid & 63;
    const int wid  = tid >> 6;             // 0..7

    if (bidx < DET_ROLE_BLOCKS) {
        float* red = (float*)&As[0][0];
        det_role(bidx / DET_BLOCKS, bidx % DET_BLOCKS, tid, 512,
                 pred0, hmap0, vm0, pred1, hmap1, vm1,
                 (float*)ws, red);
        return;
    }

    if (bidx < DET_ROLE_BLOCKS + CORR_BLOCKS) {
        // ---- sparse correction role: wave handles one (b,n) ----
        const int cid = bidx - DET_ROLE_BLOCKS;    // 0..1199
        const int idx = cid*8 + wid;               // 0..9599
        const int cb  = idx / NN, cn = idx % NN;
        const float wrow = ws[OFF_WRW + idx];
        const float wcol = ws[OFF_WCL + idx];
        const float va   = ws[OFF_VMC + idx];
        const unsigned short* tA = ta + (size_t)cb*NN*DD;
        const unsigned short* tB = tb + (size_t)cb*NN*DD;
        const float* wvmc = ws + OFF_WVMC + cb*NN;

        const int sg = lane >> 1;
        const int e  = (lane & 1) * 4;
        const unsigned short* ap = tA + ((size_t)sg*NN + cn)*8 + e;
        float a0 = bf2f(ap[0]), a1 = bf2f(ap[1]), a2 = bf2f(ap[2]), a3 = bf2f(ap[3]);

        const int ibase = (int)floorf((wrow - 4.f) * 0.125f);
        const int jbase = (int)floorf((wcol - 4.f) * 0.125f);
        float corr = 0.f;
        #pragma unroll
        for (int di = 0; di < 2; ++di) {
            #pragma unroll
            for (int dj = 0; dj < 2; ++dj) {
                int ii = ibase + di, jj = jbase + dj;
                float dr = (float)(ii*8 + 4) - wrow;
                float dc = (float)(jj*8 + 4) - wcol;
                bool ok = (ii >= 0) && (ii < HC) && (jj >= 0) && (jj < WC)
                          && (dr*dr + dc*dc) <= 56.25f;
                if (ok) {
                    int m = ii*WC + jj;
                    const unsigned short* bp = tB + ((size_t)sg*NN + m)*8 + e;
                    float d = a0*bf2f(bp[0]);
                    d = fmaf(a1, bf2f(bp[1]), d);
                    d = fmaf(a2, bf2f(bp[2]), d);
                    d = fmaf(a3, bf2f(bp[3]), d);
                    #pragma unroll
                    for (int off = 1; off < 64; off <<= 1)
                        d += __shfl_xor(d, off, 64);
                    float dotr = fmaxf(d, 0.f);
                    float pos = 250.f * fmaxf(1.f - dotr, 0.f);
                    float neg = fmaxf(d - 0.2f, 0.f);   // == what dense added
                    corr += (pos - neg) * va * wvmc[m];
                }
            }
        }
        if (lane == 0) corr_red[wid] = corr;
        __syncthreads();
        if (tid == 0) {
            float c = 0.f;
            #pragma unroll
            for (int w = 0; w < 8; ++w) c += corr_red[w];
            partials[bidx - DET_ROLE_BLOCKS] = c;
        }
        return;
    }

    // ---- GEMM role ----
    const int g = bidx - DET_ROLE_BLOCKS - CORR_BLOCKS;    // 0..1249
    // bijective XCD swizzle (m204; GEMM_BLOCKS % 8 != 0)
    const int xcd = g & 7, oi = g >> 3;
    const int q = GEMM_BLOCKS / 8, r = GEMM_BLOCKS % 8;    // 156, 2
    const int swz = (xcd < r ? xcd*(q+1) : r*(q+1) + (xcd - r)*q) + oi;
    const int b   = swz / BLK192;
    const int rr  = swz % BLK192;
    const int n0  = (rr / NT192) * TS4;
    const int m0  = (rr % NT192) * TS4;

    const unsigned short* tab = ta + (size_t)b*NN*DD;
    const unsigned short* tbb = tb + (size_t)b*NN*DD;

    // LDS: 16B segment o = s*TS4 + row (s 0..3, row 0..191) at byte o*16.
    // 24 chunks of 64 segments (12 A + 12 B); wave w issues chunks w*3..w*3+2
    // -> exactly 3 global_load_lds per wave per stage.
#define STAGE(t_, buf_)                                                          \
    {                                                                            \
        _Pragma("unroll")                                                        \
        for (int c = 0; c < 3; ++c) {                                            \
            int c2 = wid*3 + c;                                                  \
            int cA = (c2 < 12) ? c2 : (c2 - 12);                                 \
            int o  = cA*64 + lane;                                               \
            int s  = o / TS4;                                                    \
            int rr2 = o - s*TS4;                                                 \
            const unsigned short* gp = (c2 < 12)                                 \
                ? (tab + ((size_t)((t_)*4 + s)*NN + n0 + rr2)*8)                 \
                : (tbb + ((size_t)((t_)*4 + s)*NN + m0 + rr2)*8);                \
            unsigned short* l0 = (c2 < 12) ? &As[buf_][cA*512] : &Bs[buf_][cA*512];\
            __builtin_amdgcn_global_load_lds(                                    \
                (const __attribute__((address_space(1))) void*)gp,               \
                (__attribute__((address_space(3))) void*)l0, 16, 0, 0);          \
        }                                                                        \
    }

    const int wr = wid >> 2;               // 0..1: 96-row panel
    const int wc = wid & 3;                // 0..3: 48-col panel
    const int ln15   = lane & 15;
    const int slot16 = lane >> 4;          // 0..3: k-slot within BK=32 row
    f32x4 acc[6][3] = {};

    STAGE(0, 0);

    #pragma unroll
    for (int t = 0; t < 8; ++t) {
        // only stage t outstanding here -> vmcnt(0) == counted wait
        asm volatile("s_waitcnt vmcnt(0)" ::: "memory");
        __builtin_amdgcn_s_barrier();          // buf[t&1] landed; buf[(t+1)&1] free
        __builtin_amdgcn_sched_barrier(0);     // pin everything below barrier
        if (t < 7) STAGE(t+1, (t+1)&1);        // 1-deep prefetch into free buffer
        const unsigned short* Ab = As[t & 1];
        const unsigned short* Bb = Bs[t & 1];
        short8 af[6], bf[3];
        #pragma unroll
        for (int f = 0; f < 6; ++f) {
            int ra = wr*96 + f*16 + ln15;
            af[f] = *(const short8*)(Ab + (slot16*TS4 + ra)*8);
        }
        #pragma unroll
        for (int f = 0; f < 3; ++f) {
            int rb = wc*48 + f*16 + ln15;
            bf[f] = *(const short8*)(Bb + (slot16*TS4 + rb)*8);
        }
        __builtin_amdgcn_s_setprio(1);
        #pragma unroll
        for (int fi = 0; fi < 6; ++fi)
            #pragma unroll
            for (int fj = 0; fj < 3; ++fj)
                acc[fi][fj] = __builtin_amdgcn_mfma_f32_16x16x32_bf16(
                    af[fi], bf[fj], acc[fi][fj], 0, 0, 0);
        __builtin_amdgcn_s_setprio(0);
        // MFMA operand use drains this step's ds_reads before next barrier.
    }

    // ---- lean epilogue ----
    float sum = 0.f;
    #pragma unroll
    for (int fi = 0; fi < 6; ++fi)
        #pragma unroll
        for (int fj = 0; fj < 3; ++fj)
            #pragma unroll
            for (int reg = 0; reg < 4; ++reg)
                sum += fmaxf(acc[fi][fj][reg] - 0.2f, 0.f);

    float* red = (float*)&As[0][0];
    red[tid] = sum; __syncthreads();
    for (int s = 256; s > 0; s >>= 1) { if (tid < s) red[tid] += red[tid+s]; __syncthreads(); }
    if (tid == 0) partials[bidx - DET_ROLE_BLOCKS] = red[0];
#undef STAGE
}

// ---------------- fp32 fallback descriptor loss (known-good) ----------------
__global__ __launch_bounds__(256) void desc_kernel(
    const float* __restrict__ desc, const float* __restrict__ wdesc,
    const float* __restrict__ ws, float* __restrict__ partials)
{
    const int b  = blockIdx.z;
    const int n0 = blockIdx.y * 64;
    const int m0 = blockIdx.x * 64;
    const float* A  = desc  + (size_t)b*DD*NN;
    const float* Bm = wdesc + (size_t)b*DD*NN;

    __shared__ float As[32][64];
    __shared__ float Bs[32][64];

    const int tid = threadIdx.x;
    const int tx = tid & 15, ty = tid >> 4;
    float acc[4][4] = {{0.f}};

    for (int k0 = 0; k0 < DD; k0 += 32) {
        #pragma unroll
        for (int l = 0; l < 8; ++l) {
            int e = tid + l*256;
            int kk = e >> 6, nn = e & 63;
            As[kk][nn] = A [(size_t)(k0+kk)*NN + n0 + nn];
            Bs[kk][nn] = Bm[(size_t)(k0+kk)*NN + m0 + nn];
        }
        __syncthreads();
        #pragma unroll
        for (int kk = 0; kk < 32; ++kk) {
            float4 av = *reinterpret_cast<const float4*>(&As[kk][ty*4]);
            float4 bv = *reinterpret_cast<const float4*>(&Bs[kk][tx*4]);
            float a4[4] = {av.x, av.y, av.z, av.w};
            float b4[4] = {bv.x, bv.y, bv.z, bv.w};
            #pragma unroll
            for (int r = 0; r < 4; ++r)
                #pragma unroll
                for (int c = 0; c < 4; ++c)
                    acc[r][c] = fmaf(a4[r], b4[c], acc[r][c]);
        }
        __syncthreads();
    }

    const float* inva = ws + OFF_INVA + b*NN;
    const float* invb = ws + OFF_INVB + b*NN;
    const float* wrp  = ws + OFF_WRW + b*NN;
    const float* wcp  = ws + OFF_WCL + b*NN;
    const float* vmc  = ws + OFF_VMC + b*NN;
    const float* wvmc = ws + OFF_WVMC + b*NN;

    int nb = n0 + ty*4, mb = m0 + tx*4;
    float ia[4], wrv[4], wcv[4], va[4];
    #pragma unroll
    for (int r = 0; r < 4; ++r) {
        int n = nb + r;
        ia[r] = inva[n]; wrv[r] = wrp[n]; wcv[r] = wcp[n]; va[r] = vmc[n];
    }
    float ib[4], vb[4], crow[4], ccol[4];
    #pragma unroll
    for (int c = 0; c < 4; ++c) {
        int m = mb + c;
        ib[c] = invb[m]; vb[c] = wvmc[m];
        crow[c] = (float)((m / WC)*8 + 4);
        ccol[c] = (float)((m % WC)*8 + 4);
    }
    float sum = 0.f;
    #pragma unroll
    for (int r = 0; r < 4; ++r) {
        #pragma unroll
        for (int c = 0; c < 4; ++c) {
            float dot = fmaxf(acc[r][c] * ia[r] * ib[c], 0.f);
            float dr = crow[c] - wrv[r];
            float dc = ccol[c] - wcv[r];
            bool s = (dr*dr + dc*dc) <= 56.25f;
            float term = s ? 250.f * fmaxf(1.f - dot, 0.f)
                           : fmaxf(dot - 0.2f, 0.f);
            sum += term * va[r] * vb[c];
        }
    }

    __shared__ float red[256];
    red[tid] = sum; __syncthreads();
    for (int s = 128; s > 0; s >>= 1) { if (tid < s) red[tid] += red[tid+s]; __syncthreads(); }
    if (tid == 0) {
        int bid = (blockIdx.z * gridDim.y + blockIdx.y) * gridDim.x + blockIdx.x;
        partials[bid] = red[0];
    }
}

// ---------------- finalize: deterministic reduction + outputs ----------------
__global__ __launch_bounds__(256) void finalize_kernel(
    const float* __restrict__ ws, float* __restrict__ out, int desc_nblocks)
{
    __shared__ float red[256];
    int t = threadIdx.x;
    float res[2];
    float norm = 0.f;
    for (int pass = 0; pass < 2; ++pass) {
        const float* p = ws + (pass == 0 ? OFF_DET0 : OFF_DET1);
        float s0=0.f, s1=0.f, s2=0.f, s3=0.f;
        for (int i = t; i < DET_BLOCKS; i += 256) {
            s0 += p[i*4+0]; s1 += p[i*4+1]; s2 += p[i*4+2]; s3 += p[i*4+3];
        }
        float v[4] = {s0,s1,s2,s3};
        float tot[4];
        for (int j = 0; j < 4; ++j) {
            red[t] = v[j]; __syncthreads();
            for (int s = 128; s > 0; s >>= 1) { if (t < s) red[t] += red[t+s]; __syncthreads(); }
            tot[j] = red[0]; __syncthreads();
        }
        float posl = tot[0], negl = tot[1], npos = tot[2], vsum = tot[3];
        res[pass] = (npos == 0.f) ? -negl : -(posl + negl) / fmaxf(npos, 1.f);
        if (pass == 1) norm = vsum;   // normalization = wvm.sum()
    }
    float ds = 0.f;
    for (int i = t; i < desc_nblocks; i += 256) ds += ws[OFF_DESCP + i];
    red[t] = ds; __syncthreads();
    for (int s = 128; s > 0; s >>= 1) { if (t < s) red[t] += red[t+s]; __syncthreads(); }
    float descsum = red[0];
    if (t == 0) {
        float desc_loss = descsum / norm;
        float total = res[0] + res[1] + 1e-4f * desc_loss;
        out[0] = total;
        out[1] = res[0];
        out[2] = res[1];
        out[3] = desc_loss;
    }
}

extern "C" void kernel_launch(void* const* d_in, const int* in_sizes, int n_in,
                              void* d_out, int out_size, void* d_ws, size_t ws_size,
                              hipStream_t stream)
{
    const float* prob  = (const float*)d_in[0];
    const float* htm   = (const float*)d_in[1];
    const float* vmask = (const float*)d_in[2];
    const float* wprob = (const float*)d_in[3];
    const float* wht   = (const float*)d_in[4];
    const float* wvm   = (const float*)d_in[5];
    const float* desc  = (const float*)d_in[6];
    const float* wdesc = (const float*)d_in[7];
    const float* Hm    = (const float*)d_in[8];
    float* ws  = (float*)d_ws;
    float* out = (float*)d_out;

    if (ws_size >= WS_NEED) {
        unsigned short* ta = (unsigned short*)(ws + OFF_TA);
        unsigned short* tb = (unsigned short*)(ws + OFF_TB);
        phase1_kernel<<<P1_BLOCKS, 256, 0, stream>>>(desc, wdesc, vmask, wvm, Hm, ws);
        transpose_kernel<<<dim3(NN/64, DD/64, BB*2), 256, 0, stream>>>(desc, wdesc, ta, tb, ws);
        desc_mfma<<<DESC_GRID, 512, 0, stream>>>(
            ta, tb, prob, htm, vmask, wprob, wht, wvm, ws, ws + OFF_DESCP);
        finalize_kernel<<<1, 256, 0, stream>>>(ws, out, DESC_PARTIALS);
    } else {
        det_kernel<<<2*DET_BLOCKS, 256, 0, stream>>>(
            prob, htm, vmask, wprob, wht, wvm, ws);
        prep_kernel_full<<<(BB*NN + 255)/256, 256, 0, stream>>>(desc, wdesc, vmask, wvm, Hm, ws);
        desc_kernel<<<dim3(NTILES64, NTILES64, BB), 256, 0, stream>>>(desc, wdesc, ws, ws + OFF_DESCP);
        finalize_kernel<<<1, 256, 0, stream>>>(ws, out, DESC_BLOCKS_F32);
    }
}

// Round 20
// 57.531 us; speedup vs baseline: 1.0094x; 1.0094x over previous
//
#include <hip/hip_runtime.h>
#include <hip/hip_bf16.h>
#include <cmath>

// Problem dims (fixed by reference setup_inputs)
#define BB 2
#define HH 480
#define WW 640
#define DD 256
#define HC 60
#define WC 80
#define NN (HC*WC)            // 4800

#define DET_BLOCKS 300
#define SUMSQ_NB ((NN + 255)/256)         // 19
#define GEOM_NB ((BB*NN + 255)/256)       // 38
#define P1_BLOCKS (16*SUMSQ_NB + GEOM_NB) // 304 + 38 = 342

// fp32 fallback tiling
#define NTILES64 (NN/64)                  // 75
#define DESC_BLOCKS_F32 (BB*NTILES64*NTILES64)  // 11250
// mfma tiling: 192x192 block, 8 waves (2x4) of 96x48 (6x3 frags), BK=32, 3-buf
#define TS4 192
#define BK 32
#define NT192 (NN/TS4)                    // 25
#define BLK192 (NT192*NT192)              // 625
#define GEMM_BLOCKS (BB*BLK192)           // 1250
#define CORR_BLOCKS (BB*NN/8)             // 1200 (8 waves/block, 1 n per wave)
#define DET_ROLE_BLOCKS (2*DET_BLOCKS)    // 600
#define DESC_PARTIALS (GEMM_BLOCKS + CORR_BLOCKS)       // 2450
#define DESC_GRID (DESC_PARTIALS + DET_ROLE_BLOCKS)     // 3050

// ws layout (float offsets)
#define OFF_DET0  0                       // 300*4
#define OFF_DET1  2048                    // 300*4
#define OFF_INVA  16384                   // BB*NN (fallback path only)
#define OFF_INVB  (OFF_INVA + BB*NN)
#define OFF_WRW   (OFF_INVB + BB*NN)
#define OFF_WCL   (OFF_WRW + BB*NN)
#define OFF_VMC   (OFF_WCL + BB*NN)
#define OFF_WVMC  (OFF_VMC + BB*NN)
#define OFF_SQP   (OFF_WVMC + BB*NN)      // 73984; 16*NN = 76800 floats
#define OFF_DESCP (OFF_SQP + 16*NN)       // 150784; 2450 partials
#define OFF_TA    172032                  // bf16 desc, k-major [B][32][N][8] (normalized*masked)
#define TA_FLOATS (BB*NN*DD/2)            // 1228800 floats (bf16 storage)
#define OFF_TB    (OFF_TA + TA_FLOATS)
#define WS_NEED   ((size_t)(OFF_TB + TA_FLOATS) * 4)

typedef __attribute__((ext_vector_type(8))) short short8;
typedef __attribute__((ext_vector_type(4))) float f32x4;

__device__ inline float bf2f(unsigned short u)
{
    unsigned int x = ((unsigned int)u) << 16;
    return __builtin_bit_cast(float, x);
}

// ---------------- detector-loss accum (fast native log) ----------------
__device__ inline void det_accum(float p, float h, float v,
                                 float& posl, float& negl, float& npos, float& vsum)
{
    float omp = 1.f - p;
    if (h == 1.0f) {
        posl += __logf(p + 1e-7f) * omp*omp * v;
        npos += 1.f;
    }
    if (h < 1.0f) {
        float oh = 1.f - h;
        float w4 = oh*oh; w4 *= w4;
        negl += __logf(omp + 1e-7f) * p*p * w4 * v;
    }
    vsum += v;
}

// parametric over block size (nthr = 256 or 512)
__device__ inline void det_role(
    int set, int db, int tid, int nthr,
    const float* __restrict__ pred0, const float* __restrict__ hmap0, const float* __restrict__ vm0,
    const float* __restrict__ pred1, const float* __restrict__ hmap1, const float* __restrict__ vm1,
    float* __restrict__ ws, float* __restrict__ red)
{
    const float4* pred = (const float4*)(set ? pred1 : pred0);
    const float4* hmap = (const float4*)(set ? hmap1 : hmap0);
    const float4* vm   = (const float4*)(set ? vm1   : vm0);
    float* partials = ws + (set ? OFF_DET1 : OFF_DET0);

    float posl = 0.f, negl = 0.f, npos = 0.f, vsum = 0.f;
    const int total4 = BB*HH*WW/4;        // 307200
    for (int i = db*nthr + tid; i < total4; i += DET_BLOCKS*nthr) {
        float4 p = pred[i], h = hmap[i], v = vm[i];
        det_accum(p.x, h.x, v.x, posl, negl, npos, vsum);
        det_accum(p.y, h.y, v.y, posl, negl, npos, vsum);
        det_accum(p.z, h.z, v.z, posl, negl, npos, vsum);
        det_accum(p.w, h.w, v.w, posl, negl, npos, vsum);
    }
    float vals[4] = {posl, negl, npos, vsum};
    for (int j = 0; j < 4; ++j) {
        red[tid] = vals[j]; __syncthreads();
        for (int s = nthr >> 1; s > 0; s >>= 1) { if (tid < s) red[tid] += red[tid+s]; __syncthreads(); }
        if (tid == 0) partials[db*4 + j] = red[0];
        __syncthreads();
    }
}

// ---------------- shared helpers ----------------
__device__ inline float bilin_cell(const float* __restrict__ x, int i, int j)
{
    float sr = (i + 0.5f) * ((float)HH/(float)HC) - 0.5f;
    sr = fminf(fmaxf(sr, 0.f), (float)(HH-1));
    int r0 = (int)floorf(sr); int r1 = min(r0+1, HH-1); float wr = sr - (float)r0;
    float sc = (j + 0.5f) * ((float)WW/(float)WC) - 0.5f;
    sc = fminf(fmaxf(sc, 0.f), (float)(WW-1));
    int c0 = (int)floorf(sc); int c1 = min(c0+1, WW-1); float wc = sc - (float)c0;
    float v00 = x[r0*WW+c0], v01 = x[r0*WW+c1];
    float v10 = x[r1*WW+c0], v11 = x[r1*WW+c1];
    float e0 = v00*(1.f-wr) + v10*wr;
    float e1 = v01*(1.f-wr) + v11*wr;
    return e0*(1.f-wc) + e1*wc;
}

__device__ inline void prep_geom(int idx, const float* __restrict__ vm,
                                 const float* __restrict__ wvm,
                                 const float* __restrict__ Hmat, float* __restrict__ ws)
{
    int b = idx / NN, n = idx % NN;
    int i = n / WC, j = n % WC;
    float px = (float)(j*8 + 4), py = (float)(i*8 + 4);   // (col, row)
    const float* Hb = Hmat + b*9;  // Hmat shape (B,1,3,3)
    float w0 = Hb[0]*px + Hb[1]*py + Hb[2];
    float w1 = Hb[3]*px + Hb[4]*py + Hb[5];
    float w2 = Hb[6]*px + Hb[7]*py + Hb[8];
    ws[OFF_WRW + idx] = w1 / w2;   // warped row
    ws[OFF_WCL + idx] = w0 / w2;   // warped col
    ws[OFF_VMC  + idx] = (bilin_cell(vm  + (size_t)b*HH*WW, i, j) > 0.5f) ? 1.f : 0.f;
    ws[OFF_WVMC + idx] = (bilin_cell(wvm + (size_t)b*HH*WW, i, j) > 0.5f) ? 1.f : 0.f;
}

// ---- phase1: sumsq partials (coalesced) + geometry/masks ----
__global__ __launch_bounds__(256) void phase1_kernel(
    const float* __restrict__ desc, const float* __restrict__ wdesc,
    const float* __restrict__ vm, const float* __restrict__ wvm,
    const float* __restrict__ Hmat, float* __restrict__ ws)
{
    const int bidx = blockIdx.x;
    if (bidx < 16*SUMSQ_NB) {
        const int combo = bidx / SUMSQ_NB;         // 0..15
        const int nb    = bidx % SUMSQ_NB;
        const int z  = combo >> 2;                 // b*2 + which
        const int dc = combo & 3;                  // 64-d chunk
        const int n  = nb*256 + threadIdx.x;
        if (n >= NN) return;
        const float* src = ((z & 1) ? wdesc : desc) + (size_t)(z >> 1)*DD*NN;
        float s = 0.f;
        const int d0 = dc*64;
        #pragma unroll 8
        for (int d = d0; d < d0 + 64; ++d) {
            float v = src[(size_t)d*NN + n];
            s = fmaf(v, v, s);
        }
        ws[OFF_SQP + ((size_t)z*4 + dc)*NN + n] = s;
        return;
    }
    const int idx = (bidx - 16*SUMSQ_NB)*256 + threadIdx.x;
    if (idx >= BB*NN) return;
    prep_geom(idx, vm, wvm, Hmat, ws);
}

// ---- prep (fallback): norms via direct column loop + geometry ----
__global__ __launch_bounds__(256) void prep_kernel_full(
    const float* __restrict__ desc, const float* __restrict__ wdesc,
    const float* __restrict__ vm, const float* __restrict__ wvm,
    const float* __restrict__ Hmat, float* __restrict__ ws)
{
    int idx = blockIdx.x*256 + threadIdx.x;
    if (idx >= BB*NN) return;
    int b = idx / NN, n = idx % NN;

    const float* a  = desc  + (size_t)b*DD*NN + n;
    const float* bp = wdesc + (size_t)b*DD*NN + n;
    float sa = 0.f, sb = 0.f;
    for (int d = 0; d < DD; ++d) {
        float x = a[(size_t)d*NN];  sa = fmaf(x, x, sa);
        float y = bp[(size_t)d*NN]; sb = fmaf(y, y, sb);
    }
    ws[OFF_INVA + idx] = 1.f / fmaxf(sqrtf(sa), 1e-12f);
    ws[OFF_INVB + idx] = 1.f / fmaxf(sqrtf(sb), 1e-12f);
    prep_geom(idx, vm, wvm, Hmat, ws);
}

// ---- standalone det (fallback path) ----
__global__ __launch_bounds__(256) void det_kernel(
    const float* __restrict__ pred0, const float* __restrict__ hmap0, const float* __restrict__ vm0,
    const float* __restrict__ pred1, const float* __restrict__ hmap1, const float* __restrict__ vm1,
    float* __restrict__ ws)
{
    __shared__ float red[256];
    det_role(blockIdx.x / DET_BLOCKS, blockIdx.x % DET_BLOCKS, threadIdx.x, 256,
             pred0, hmap0, vm0, pred1, hmap1, vm1, ws, red);
}

// -------- transpose + NORMALIZE(inline from SQP) + MASK + bf16 pack --------
__global__ __launch_bounds__(256) void transpose_kernel(
    const float* __restrict__ desc, const float* __restrict__ wdesc,
    unsigned short* __restrict__ ta, unsigned short* __restrict__ tb,
    const float* __restrict__ ws)
{
    const int nb = blockIdx.x * 64;
    const int db = blockIdx.y * 64;
    const int z  = blockIdx.z;           // b*2 + which
    const int b  = z >> 1;
    const float* src = (z & 1) ? wdesc : desc;
    unsigned short* dst = (z & 1) ? tb : ta;
    src += (size_t)b*DD*NN;
    dst += (size_t)b*NN*DD;

    __shared__ float tile[64][65];
    const int tr = threadIdx.x >> 6;     // 0..3 (wave id)
    const int tc = threadIdx.x & 63;
    #pragma unroll
    for (int i = 0; i < 16; ++i) {
        int d = db + i*4 + tr;
        tile[i*4 + tr][tc] = src[(size_t)d*NN + nb + tc];
    }
    __syncthreads();
    const int n = nb + tc;
    const int gidx = b*NN + n;
    float ss = 0.f;
    #pragma unroll
    for (int k = 0; k < 4; ++k)
        ss += ws[OFF_SQP + ((size_t)z*4 + k)*NN + n];
    const float inv  = 1.f / fmaxf(sqrtf(ss), 1e-12f);
    const float mask = (z & 1) ? ws[OFF_WVMC + gidx] : ws[OFF_VMC + gidx];
    const float scl  = inv * mask;
    #pragma unroll
    for (int gg = 0; gg < 2; ++gg) {
        int g = tr + gg*4;               // 0..7 within this 64-d tile
        short8 v8;
        #pragma unroll
        for (int j = 0; j < 8; ++j) {
            float v = tile[g*8 + j][tc] * scl;
            __hip_bfloat16 h = __float2bfloat16(v);
            v8[j] = (short)__builtin_bit_cast(unsigned short, h);
        }
        int sg = (db >> 3) + g;          // global slot 0..31
        *(short8*)(dst + ((size_t)sg*NN + nb + tc)*8) = v8;   // coalesced 16B/lane
    }
}

// ---------------- MFMA descriptor loss v17 (best measured: R18) ------------
// Grid = DET -> CORR -> GEMM roles, 512 threads/block.
// GEMM role: 192x192 block, 8 waves (2x4) of 96x48 (6x3 frags 16x16x32),
// BK=32, TRIPLE-buffered LDS (72 KB), ONE s_barrier per K-step + counted
// vmcnt(3) (each wave issues exactly 3 global_load_lds per stage; 24 chunks
// / 8 waves uniform). Lean epilogue sum += relu(acc-0.2).
// CORR role: 8 waves x 1 (b,n). DET role: parametric det partials.
__global__ __launch_bounds__(512, 4) void desc_mfma(
    const unsigned short* __restrict__ ta, const unsigned short* __restrict__ tb,
    const float* __restrict__ pred0, const float* __restrict__ hmap0, const float* __restrict__ vm0,
    const float* __restrict__ pred1, const float* __restrict__ hmap1, const float* __restrict__ vm1,
    const float* __restrict__ ws, float* __restrict__ partials)
{
    __shared__ unsigned short As[3][TS4*BK];   // 36 KB
    __shared__ unsigned short Bs[3][TS4*BK];   // 72 KB total
    __shared__ float corr_red[8];

    const int bidx = blockIdx.x;
    const int tid  = threadIdx.x;
    const int lane = tid & 63;
    const int wid  = tid >> 6;             // 0..7

    if (bidx < DET_ROLE_BLOCKS) {
        float* red = (float*)&As[0][0];
        det_role(bidx / DET_BLOCKS, bidx % DET_BLOCKS, tid, 512,
                 pred0, hmap0, vm0, pred1, hmap1, vm1,
                 (float*)ws, red);
        return;
    }

    if (bidx < DET_ROLE_BLOCKS + CORR_BLOCKS) {
        // ---- sparse correction role: wave handles one (b,n) ----
        const int cid = bidx - DET_ROLE_BLOCKS;    // 0..1199
        const int idx = cid*8 + wid;               // 0..9599
        const int cb  = idx / NN, cn = idx % NN;
        const float wrow = ws[OFF_WRW + idx];
        const float wcol = ws[OFF_WCL + idx];
        const float va   = ws[OFF_VMC + idx];
        const unsigned short* tA = ta + (size_t)cb*NN*DD;
        const unsigned short* tB = tb + (size_t)cb*NN*DD;
        const float* wvmc = ws + OFF_WVMC + cb*NN;

        const int sg = lane >> 1;
        const int e  = (lane & 1) * 4;
        const unsigned short* ap = tA + ((size_t)sg*NN + cn)*8 + e;
        float a0 = bf2f(ap[0]), a1 = bf2f(ap[1]), a2 = bf2f(ap[2]), a3 = bf2f(ap[3]);

        const int ibase = (int)floorf((wrow - 4.f) * 0.125f);
        const int jbase = (int)floorf((wcol - 4.f) * 0.125f);
        float corr = 0.f;
        #pragma unroll
        for (int di = 0; di < 2; ++di) {
            #pragma unroll
            for (int dj = 0; dj < 2; ++dj) {
                int ii = ibase + di, jj = jbase + dj;
                float dr = (float)(ii*8 + 4) - wrow;
                float dc = (float)(jj*8 + 4) - wcol;
                bool ok = (ii >= 0) && (ii < HC) && (jj >= 0) && (jj < WC)
                          && (dr*dr + dc*dc) <= 56.25f;
                if (ok) {
                    int m = ii*WC + jj;
                    const unsigned short* bp = tB + ((size_t)sg*NN + m)*8 + e;
                    float d = a0*bf2f(bp[0]);
                    d = fmaf(a1, bf2f(bp[1]), d);
                    d = fmaf(a2, bf2f(bp[2]), d);
                    d = fmaf(a3, bf2f(bp[3]), d);
                    #pragma unroll
                    for (int off = 1; off < 64; off <<= 1)
                        d += __shfl_xor(d, off, 64);
                    float dotr = fmaxf(d, 0.f);
                    float pos = 250.f * fmaxf(1.f - dotr, 0.f);
                    float neg = fmaxf(d - 0.2f, 0.f);   // == what dense added
                    corr += (pos - neg) * va * wvmc[m];
                }
            }
        }
        if (lane == 0) corr_red[wid] = corr;
        __syncthreads();
        if (tid == 0) {
            float c = 0.f;
            #pragma unroll
            for (int w = 0; w < 8; ++w) c += corr_red[w];
            partials[bidx - DET_ROLE_BLOCKS] = c;
        }
        return;
    }

    // ---- GEMM role ----
    const int g = bidx - DET_ROLE_BLOCKS - CORR_BLOCKS;    // 0..1249
    // bijective XCD swizzle (m204; GEMM_BLOCKS % 8 != 0)
    const int xcd = g & 7, oi = g >> 3;
    const int q = GEMM_BLOCKS / 8, r = GEMM_BLOCKS % 8;    // 156, 2
    const int swz = (xcd < r ? xcd*(q+1) : r*(q+1) + (xcd - r)*q) + oi;
    const int b   = swz / BLK192;
    const int rr  = swz % BLK192;
    const int n0  = (rr / NT192) * TS4;
    const int m0  = (rr % NT192) * TS4;

    const unsigned short* tab = ta + (size_t)b*NN*DD;
    const unsigned short* tbb = tb + (size_t)b*NN*DD;

    // LDS: 16B segment o = s*TS4 + row (s 0..3, row 0..191) at byte o*16.
    // 24 chunks of 64 segments (12 A + 12 B); wave w issues chunks w*3..w*3+2
    // -> exactly 3 global_load_lds per wave per stage (vmcnt counting).
#define STAGE(t_, buf_)                                                          \
    {                                                                            \
        _Pragma("unroll")                                                        \
        for (int c = 0; c < 3; ++c) {                                            \
            int c2 = wid*3 + c;                                                  \
            int cA = (c2 < 12) ? c2 : (c2 - 12);                                 \
            int o  = cA*64 + lane;                                               \
            int s  = o / TS4;                                                    \
            int rr2 = o - s*TS4;                                                 \
            const unsigned short* gp = (c2 < 12)                                 \
                ? (tab + ((size_t)((t_)*4 + s)*NN + n0 + rr2)*8)                 \
                : (tbb + ((size_t)((t_)*4 + s)*NN + m0 + rr2)*8);                \
            unsigned short* l0 = (c2 < 12) ? &As[buf_][cA*512] : &Bs[buf_][cA*512];\
            __builtin_amdgcn_global_load_lds(                                    \
                (const __attribute__((address_space(1))) void*)gp,               \
                (__attribute__((address_space(3))) void*)l0, 16, 0, 0);          \
        }                                                                        \
    }

    const int wr = wid >> 2;               // 0..1: 96-row panel
    const int wc = wid & 3;                // 0..3: 48-col panel
    const int ln15   = lane & 15;
    const int slot16 = lane >> 4;          // 0..3: k-slot within BK=32 row
    f32x4 acc[6][3] = {};

    STAGE(0, 0);
    STAGE(1, 1);

    #pragma unroll
    for (int t = 0; t < 8; ++t) {
        // outstanding per wave here: stage t (3) + stage t+1 (3)
        if (t < 7) asm volatile("s_waitcnt vmcnt(3)" ::: "memory");
        else       asm volatile("s_waitcnt vmcnt(0)" ::: "memory");
        __builtin_amdgcn_s_barrier();          // buf[t%3] fully landed
        __builtin_amdgcn_sched_barrier(0);     // pin everything below barrier
        if (t < 6) STAGE(t+2, (t+2) % 3);      // deep prefetch into free buffer
        const unsigned short* Ab = As[t % 3];
        const unsigned short* Bb = Bs[t % 3];
        short8 af[6], bf[3];
        #pragma unroll
        for (int f = 0; f < 6; ++f) {
            int ra = wr*96 + f*16 + ln15;
            af[f] = *(const short8*)(Ab + (slot16*TS4 + ra)*8);
        }
        #pragma unroll
        for (int f = 0; f < 3; ++f) {
            int rb = wc*48 + f*16 + ln15;
            bf[f] = *(const short8*)(Bb + (slot16*TS4 + rb)*8);
        }
        __builtin_amdgcn_s_setprio(1);
        #pragma unroll
        for (int fi = 0; fi < 6; ++fi)
            #pragma unroll
            for (int fj = 0; fj < 3; ++fj)
                acc[fi][fj] = __builtin_amdgcn_mfma_f32_16x16x32_bf16(
                    af[fi], bf[fj], acc[fi][fj], 0, 0, 0);
        __builtin_amdgcn_s_setprio(0);
        // MFMA operand use drains this step's ds_reads before next barrier.
    }

    // ---- lean epilogue ----
    float sum = 0.f;
    #pragma unroll
    for (int fi = 0; fi < 6; ++fi)
        #pragma unroll
        for (int fj = 0; fj < 3; ++fj)
            #pragma unroll
            for (int reg = 0; reg < 4; ++reg)
                sum += fmaxf(acc[fi][fj][reg] - 0.2f, 0.f);

    float* red = (float*)&As[0][0];
    red[tid] = sum; __syncthreads();
    for (int s = 256; s > 0; s >>= 1) { if (tid < s) red[tid] += red[tid+s]; __syncthreads(); }
    if (tid == 0) partials[bidx - DET_ROLE_BLOCKS] = red[0];
#undef STAGE
}

// ---------------- fp32 fallback descriptor loss (known-good) ----------------
__global__ __launch_bounds__(256) void desc_kernel(
    const float* __restrict__ desc, const float* __restrict__ wdesc,
    const float* __restrict__ ws, float* __restrict__ partials)
{
    const int b  = blockIdx.z;
    const int n0 = blockIdx.y * 64;
    const int m0 = blockIdx.x * 64;
    const float* A  = desc  + (size_t)b*DD*NN;
    const float* Bm = wdesc + (size_t)b*DD*NN;

    __shared__ float As[32][64];
    __shared__ float Bs[32][64];

    const int tid = threadIdx.x;
    const int tx = tid & 15, ty = tid >> 4;
    float acc[4][4] = {{0.f}};

    for (int k0 = 0; k0 < DD; k0 += 32) {
        #pragma unroll
        for (int l = 0; l < 8; ++l) {
            int e = tid + l*256;
            int kk = e >> 6, nn = e & 63;
            As[kk][nn] = A [(size_t)(k0+kk)*NN + n0 + nn];
            Bs[kk][nn] = Bm[(size_t)(k0+kk)*NN + m0 + nn];
        }
        __syncthreads();
        #pragma unroll
        for (int kk = 0; kk < 32; ++kk) {
            float4 av = *reinterpret_cast<const float4*>(&As[kk][ty*4]);
            float4 bv = *reinterpret_cast<const float4*>(&Bs[kk][tx*4]);
            float a4[4] = {av.x, av.y, av.z, av.w};
            float b4[4] = {bv.x, bv.y, bv.z, bv.w};
            #pragma unroll
            for (int r = 0; r < 4; ++r)
                #pragma unroll
                for (int c = 0; c < 4; ++c)
                    acc[r][c] = fmaf(a4[r], b4[c], acc[r][c]);
        }
        __syncthreads();
    }

    const float* inva = ws + OFF_INVA + b*NN;
    const float* invb = ws + OFF_INVB + b*NN;
    const float* wrp  = ws + OFF_WRW + b*NN;
    const float* wcp  = ws + OFF_WCL + b*NN;
    const float* vmc  = ws + OFF_VMC + b*NN;
    const float* wvmc = ws + OFF_WVMC + b*NN;

    int nb = n0 + ty*4, mb = m0 + tx*4;
    float ia[4], wrv[4], wcv[4], va[4];
    #pragma unroll
    for (int r = 0; r < 4; ++r) {
        int n = nb + r;
        ia[r] = inva[n]; wrv[r] = wrp[n]; wcv[r] = wcp[n]; va[r] = vmc[n];
    }
    float ib[4], vb[4], crow[4], ccol[4];
    #pragma unroll
    for (int c = 0; c < 4; ++c) {
        int m = mb + c;
        ib[c] = invb[m]; vb[c] = wvmc[m];
        crow[c] = (float)((m / WC)*8 + 4);
        ccol[c] = (float)((m % WC)*8 + 4);
    }
    float sum = 0.f;
    #pragma unroll
    for (int r = 0; r < 4; ++r) {
        #pragma unroll
        for (int c = 0; c < 4; ++c) {
            float dot = fmaxf(acc[r][c] * ia[r] * ib[c], 0.f);
            float dr = crow[c] - wrv[r];
            float dc = ccol[c] - wcv[r];
            bool s = (dr*dr + dc*dc) <= 56.25f;
            float term = s ? 250.f * fmaxf(1.f - dot, 0.f)
                           : fmaxf(dot - 0.2f, 0.f);
            sum += term * va[r] * vb[c];
        }
    }

    __shared__ float red[256];
    red[tid] = sum; __syncthreads();
    for (int s = 128; s > 0; s >>= 1) { if (tid < s) red[tid] += red[tid+s]; __syncthreads(); }
    if (tid == 0) {
        int bid = (blockIdx.z * gridDim.y + blockIdx.y) * gridDim.x + blockIdx.x;
        partials[bid] = red[0];
    }
}

// ---------------- finalize: deterministic reduction + outputs ----------------
__global__ __launch_bounds__(256) void finalize_kernel(
    const float* __restrict__ ws, float* __restrict__ out, int desc_nblocks)
{
    __shared__ float red[256];
    int t = threadIdx.x;
    float res[2];
    float norm = 0.f;
    for (int pass = 0; pass < 2; ++pass) {
        const float* p = ws + (pass == 0 ? OFF_DET0 : OFF_DET1);
        float s0=0.f, s1=0.f, s2=0.f, s3=0.f;
        for (int i = t; i < DET_BLOCKS; i += 256) {
            s0 += p[i*4+0]; s1 += p[i*4+1]; s2 += p[i*4+2]; s3 += p[i*4+3];
        }
        float v[4] = {s0,s1,s2,s3};
        float tot[4];
        for (int j = 0; j < 4; ++j) {
            red[t] = v[j]; __syncthreads();
            for (int s = 128; s > 0; s >>= 1) { if (t < s) red[t] += red[t+s]; __syncthreads(); }
            tot[j] = red[0]; __syncthreads();
        }
        float posl = tot[0], negl = tot[1], npos = tot[2], vsum = tot[3];
        res[pass] = (npos == 0.f) ? -negl : -(posl + negl) / fmaxf(npos, 1.f);
        if (pass == 1) norm = vsum;   // normalization = wvm.sum()
    }
    float ds = 0.f;
    for (int i = t; i < desc_nblocks; i += 256) ds += ws[OFF_DESCP + i];
    red[t] = ds; __syncthreads();
    for (int s = 128; s > 0; s >>= 1) { if (t < s) red[t] += red[t+s]; __syncthreads(); }
    float descsum = red[0];
    if (t == 0) {
        float desc_loss = descsum / norm;
        float total = res[0] + res[1] + 1e-4f * desc_loss;
        out[0] = total;
        out[1] = res[0];
        out[2] = res[1];
        out[3] = desc_loss;
    }
}

extern "C" void kernel_launch(void* const* d_in, const int* in_sizes, int n_in,
                              void* d_out, int out_size, void* d_ws, size_t ws_size,
                              hipStream_t stream)
{
    const float* prob  = (const float*)d_in[0];
    const float* htm   = (const float*)d_in[1];
    const float* vmask = (const float*)d_in[2];
    const float* wprob = (const float*)d_in[3];
    const float* wht   = (const float*)d_in[4];
    const float* wvm   = (const float*)d_in[5];
    const float* desc  = (const float*)d_in[6];
    const float* wdesc = (const float*)d_in[7];
    const float* Hm    = (const float*)d_in[8];
    float* ws  = (float*)d_ws;
    float* out = (float*)d_out;

    if (ws_size >= WS_NEED) {
        unsigned short* ta = (unsigned short*)(ws + OFF_TA);
        unsigned short* tb = (unsigned short*)(ws + OFF_TB);
        phase1_kernel<<<P1_BLOCKS, 256, 0, stream>>>(desc, wdesc, vmask, wvm, Hm, ws);
        transpose_kernel<<<dim3(NN/64, DD/64, BB*2), 256, 0, stream>>>(desc, wdesc, ta, tb, ws);
        desc_mfma<<<DESC_GRID, 512, 0, stream>>>(
            ta, tb, prob, htm, vmask, wprob, wht, wvm, ws, ws + OFF_DESCP);
        finalize_kernel<<<1, 256, 0, stream>>>(ws, out, DESC_PARTIALS);
    } else {
        det_kernel<<<2*DET_BLOCKS, 256, 0, stream>>>(
            prob, htm, vmask, wprob, wht, wvm, ws);
        prep_kernel_full<<<(BB*NN + 255)/256, 256, 0, stream>>>(desc, wdesc, vmask, wvm, Hm, ws);
        desc_kernel<<<dim3(NTILES64, NTILES64, BB), 256, 0, stream>>>(desc, wdesc, ws, ws + OFF_DESCP);
        finalize_kernel<<<1, 256, 0, stream>>>(ws, out, DESC_BLOCKS_F32);
    }
}